// Round 6
// baseline (161.428 us; speedup 1.0000x reference)
//
#include <hip/hip_runtime.h>
#include <math.h>

// Problem constants (reference: B=4, T=4096, D_MODEL=128, N_HEADS=4, HEAD_DIM=32)
#define B_   4
#define T_   4096
#define DM_  128
#define NH_  4
#define HD_  32
#define TOKENS (B_ * T_)               // 16384

typedef __attribute__((ext_vector_type(8))) short short8;   // 8 bf16 = 4 VGPRs (MFMA A/B frag)
typedef __attribute__((ext_vector_type(4))) float floatx4;  // MFMA C/D frag

__device__ __forceinline__ unsigned short f2bf(float f) {
    union { float f; unsigned int u; } v; v.f = f;
    unsigned int u = v.u;
    u += 0x7fffu + ((u >> 16) & 1u);   // round-to-nearest-even
    return (unsigned short)(u >> 16);
}
__device__ __forceinline__ void split_bf(float v, unsigned short& hi, unsigned short& lo) {
    unsigned short h = f2bf(v);
    float hf = __uint_as_float(((unsigned int)h) << 16);
    hi = h;
    lo = f2bf(v - hf);
}

// LDS row stride for bf16 W tiles: 128 elements + 8 pad = 136 shorts = 272 B.
#define LROW 136

// -------------------------------------------------------------------------
// Kernel 1: QKV projection via MFMA, hi/lo bf16 split.
// grid (M/64, 6).  Q/K chunks: C = x·W^T (stores along d, 32B segments).
// V chunks: C^T = W·x^T (SWAPPED operands) so v_t (bh,32,t) stores are
// 32B t-segments instead of 8B scatters.
// Outputs: Q bf16 PRE-SCALED by log2(e)/sqrt(32); K bf16; V^T bf16.
// -------------------------------------------------------------------------
__global__ __launch_bounds__(256) void qkv_proj_kernel(
    const float* __restrict__ x, const float* __restrict__ Wqkv,
    unsigned short* __restrict__ q_bf, unsigned short* __restrict__ k_bf,
    unsigned short* __restrict__ v_t)
{
    __shared__ __align__(16) unsigned short whi[64 * LROW];   // 17 KB
    __shared__ __align__(16) unsigned short wlo[64 * LROW];   // 17 KB

    const int tid  = threadIdx.x;
    const int wave = tid >> 6, lane = tid & 63;
    const int m    = lane & 15, q4 = lane >> 4;
    const int m0   = blockIdx.x * 64;
    const int ch   = blockIdx.y;                  // 0..5
    const float scale = 0.2550052509571414f;      // log2(e)/sqrt(32)

    {   // cooperative W chunk split: rows ch*64 .. +63
        const float4* wg = (const float4*)(Wqkv + (size_t)ch * 64 * DM_);
        #pragma unroll
        for (int i = 0; i < 8; ++i) {
            const int f = tid + 256 * i;
            float4 v = wg[f];
            const int row = f >> 5, k4 = f & 31;
            ushort4 h, l;
            split_bf(v.x, h.x, l.x); split_bf(v.y, h.y, l.y);
            split_bf(v.z, h.z, l.z); split_bf(v.w, h.w, l.w);
            *(ushort4*)(whi + row * LROW + k4 * 4) = h;
            *(ushort4*)(wlo + row * LROW + k4 * 4) = l;
        }
    }

    // x frags direct from global: row m0+wave*16+m (serves as A or B — same layout)
    short8 Ah[4], Al[4];
    {
        const float4* xg = (const float4*)(x + (size_t)(m0 + wave * 16 + m) * DM_);
        #pragma unroll
        for (int ks = 0; ks < 4; ++ks) {
            float4 a = xg[ks * 8 + q4 * 2];
            float4 b = xg[ks * 8 + q4 * 2 + 1];
            ushort4 h0, l0, h1, l1;
            split_bf(a.x, h0.x, l0.x); split_bf(a.y, h0.y, l0.y);
            split_bf(a.z, h0.z, l0.z); split_bf(a.w, h0.w, l0.w);
            split_bf(b.x, h1.x, l1.x); split_bf(b.y, h1.y, l1.y);
            split_bf(b.z, h1.z, l1.z); split_bf(b.w, h1.w, l1.w);
            Ah[ks] = short8{(short)h0.x, (short)h0.y, (short)h0.z, (short)h0.w,
                            (short)h1.x, (short)h1.y, (short)h1.z, (short)h1.w};
            Al[ks] = short8{(short)l0.x, (short)l0.y, (short)l0.z, (short)l0.w,
                            (short)l1.x, (short)l1.y, (short)l1.z, (short)l1.w};
        }
    }
    __syncthreads();

    const int b    = m0 >> 12;
    const int tloc = (m0 & (T_ - 1)) + wave * 16;

    if (ch < 4) {   // Q (ch 0,1) and K (ch 2,3): C = x·W^T
        #pragma unroll
        for (int nb = 0; nb < 4; ++nb) {
            floatx4 acc = {0.f, 0.f, 0.f, 0.f};
            #pragma unroll
            for (int ks = 0; ks < 4; ++ks) {
                short8 Bh = *(const short8*)(whi + (nb * 16 + m) * LROW + ks * 32 + q4 * 8);
                short8 Bl = *(const short8*)(wlo + (nb * 16 + m) * LROW + ks * 32 + q4 * 8);
                acc = __builtin_amdgcn_mfma_f32_16x16x32_bf16(Ah[ks], Bh, acc, 0, 0, 0);
                acc = __builtin_amdgcn_mfma_f32_16x16x32_bf16(Ah[ks], Bl, acc, 0, 0, 0);
                acc = __builtin_amdgcn_mfma_f32_16x16x32_bf16(Al[ks], Bh, acc, 0, 0, 0);
            }
            const int n  = ch * 64 + nb * 16 + m;   // col = lane m
            const int hh = (n >> 5) & 3;
            const int d  = n & 31;
            const int bh = b * NH_ + hh;
            const int t0 = tloc + q4 * 4;           // row = q4*4+reg
            if (ch < 2) {
                #pragma unroll
                for (int reg = 0; reg < 4; ++reg)
                    q_bf[((size_t)bh * T_ + t0 + reg) * HD_ + d] = f2bf(acc[reg] * scale);
            } else {
                #pragma unroll
                for (int reg = 0; reg < 4; ++reg)
                    k_bf[((size_t)bh * T_ + t0 + reg) * HD_ + d] = f2bf(acc[reg]);
            }
        }
    } else {        // V (ch 4,5): C^T = W·x^T — rows = W n-index, cols = tokens
        #pragma unroll
        for (int nb = 0; nb < 4; ++nb) {
            floatx4 acc = {0.f, 0.f, 0.f, 0.f};
            #pragma unroll
            for (int ks = 0; ks < 4; ++ks) {
                short8 Bh = *(const short8*)(whi + (nb * 16 + m) * LROW + ks * 32 + q4 * 8);
                short8 Bl = *(const short8*)(wlo + (nb * 16 + m) * LROW + ks * 32 + q4 * 8);
                acc = __builtin_amdgcn_mfma_f32_16x16x32_bf16(Bh, Ah[ks], acc, 0, 0, 0);
                acc = __builtin_amdgcn_mfma_f32_16x16x32_bf16(Bh, Al[ks], acc, 0, 0, 0);
                acc = __builtin_amdgcn_mfma_f32_16x16x32_bf16(Bl, Ah[ks], acc, 0, 0, 0);
            }
            const int t = tloc + m;                 // col = token (lane m)
            #pragma unroll
            for (int reg = 0; reg < 4; ++reg) {     // row = n local = q4*4+reg
                const int n  = ch * 64 + nb * 16 + q4 * 4 + reg;
                const int hh = (n >> 5) & 3;
                const int d  = n & 31;
                v_t[((size_t)(b * NH_ + hh) * HD_ + d) * T_ + t] = f2bf(acc[reg]);
            }
        }
    }
}

// -------------------------------------------------------------------------
// Kernel 2: bf16 MFMA causal flash attention — WAVE-AUTONOMOUS.
// One wave owns a 32-row Q-tile (2048 waves, 8/CU). No barriers, no K/V LDS:
// Q/K/V MFMA fragments load directly from global (L2-resident, XCD swizzle).
// LDS only for the P^T round-trip.  Row-sum l via ones-row MFMA (rides the
// O accumulator through alpha rescales).  exp2-domain softmax.
// Block = 4 independent waves with qt in {u,127-u,64+u,63-u} (balanced).
// -------------------------------------------------------------------------
__global__ __launch_bounds__(256) void attn_mfma_kernel(
    const unsigned short* __restrict__ qb, const unsigned short* __restrict__ kb,
    const unsigned short* __restrict__ vtb, float* __restrict__ og)
{
    __shared__ __align__(16) char pSm[4 * 32 * 144];   // 18 KB: per-wave P^T
    const int tid  = threadIdx.x;
    const int wave = tid >> 6, lane = tid & 63;
    const int m    = lane & 15, q4 = lane >> 4;
    char* pT = pSm + wave * 4608;                      // 32 q-rows x 144 B

    // blockIdx: xcd = b&7 (2 heads/XCD), g = b>>3: bh = 2*xcd + (g&1), u = g>>1
    const int bidx = blockIdx.x;                       // 0..511
    const int xcd  = bidx & 7;
    const int g    = bidx >> 3;                        // 0..63
    const int bh   = xcd * 2 + (g & 1);
    const int u    = g >> 1;                           // 0..31
    const int qt   = (wave == 0) ? u : (wave == 1) ? 127 - u
                   : (wave == 2) ? 64 + u : 63 - u;    // 32-row q-tile, 0..127

    const size_t qkbase = (size_t)bh * T_ * HD_;
    const char* kg = (const char*)(kb + qkbase);
    const char* vg = (const char*)(vtb + qkbase);      // (d,t), row stride T_*2 B
    const char* qg = (const char*)(qb + qkbase);

    // Q B-frags (2 x 16 rows), loaded once
    short8 qf[2];
    #pragma unroll
    for (int qb_ = 0; qb_ < 2; ++qb_)
        qf[qb_] = *(const short8*)(qg + (size_t)(qt * 32 + qb_ * 16 + m) * 64 + q4 * 16);

    // ones A-frag: V-row "32" = all ones (row-sum accumulator)
    const short ob = (short)0x3F80;
    const short8 onesf = (m == 0) ? short8{ob, ob, ob, ob, ob, ob, ob, ob}
                                  : short8{0, 0, 0, 0, 0, 0, 0, 0};

    floatx4 O[2][2] = {{{0.f,0.f,0.f,0.f},{0.f,0.f,0.f,0.f}},
                       {{0.f,0.f,0.f,0.f},{0.f,0.f,0.f,0.f}}};   // [dblk][qb_]
    floatx4 Cs[2] = {{0.f,0.f,0.f,0.f},{0.f,0.f,0.f,0.f}};       // l rows
    float mx[2] = {-INFINITY, -INFINITY};

    const int ktN = (qt * 32 + 31) >> 6;   // last 64-col KV tile

    for (int kt = 0; kt <= ktN; ++kt) {
        // K A-frags (4 x 16 s-rows) and V^T A-frags (2 dblk x 2 s-halves), from global
        short8 kf[4];
        #pragma unroll
        for (int sb = 0; sb < 4; ++sb)
            kf[sb] = *(const short8*)(kg + (size_t)(kt * 64 + sb * 16 + m) * 64 + q4 * 16);
        short8 vf[2][2];
        #pragma unroll
        for (int db = 0; db < 2; ++db)
            #pragma unroll
            for (int h = 0; h < 2; ++h)
                vf[db][h] = *(const short8*)(vg + (size_t)(db * 16 + m) * (T_ * 2)
                                                + kt * 128 + h * 64 + q4 * 16);

        // S^T = K·Q^T : C[s=q4*4+reg][q=m]
        floatx4 st[4][2];
        #pragma unroll
        for (int sb = 0; sb < 4; ++sb)
            #pragma unroll
            for (int qb_ = 0; qb_ < 2; ++qb_) {
                floatx4 z = {0.f, 0.f, 0.f, 0.f};
                st[sb][qb_] = __builtin_amdgcn_mfma_f32_16x16x32_bf16(kf[sb], qf[qb_], z, 0, 0, 0);
            }

        if (kt == ktN) {   // causal mask on the last tile
            #pragma unroll
            for (int sb = 0; sb < 4; ++sb)
                #pragma unroll
                for (int qb_ = 0; qb_ < 2; ++qb_) {
                    const int qloc = ((qt & 1) << 5) + qb_ * 16 + m;
                    #pragma unroll
                    for (int reg = 0; reg < 4; ++reg)
                        if (sb * 16 + q4 * 4 + reg > qloc) st[sb][qb_][reg] = -INFINITY;
                }
        }

        // online softmax per qb_ (per-lane scalar stats; 2 cross-quad shuffles)
        #pragma unroll
        for (int qb_ = 0; qb_ < 2; ++qb_) {
            float rmax = -INFINITY;
            #pragma unroll
            for (int sb = 0; sb < 4; ++sb)
                #pragma unroll
                for (int reg = 0; reg < 4; ++reg) rmax = fmaxf(rmax, st[sb][qb_][reg]);
            rmax = fmaxf(rmax, __shfl_xor(rmax, 16, 64));
            rmax = fmaxf(rmax, __shfl_xor(rmax, 32, 64));
            const float mn = fmaxf(mx[qb_], rmax);
            const float alpha = __builtin_amdgcn_exp2f(mx[qb_] - mn);  // 0 on first tile
            mx[qb_] = mn;
            #pragma unroll
            for (int db = 0; db < 2; ++db)
                #pragma unroll
                for (int reg = 0; reg < 4; ++reg) O[db][qb_][reg] *= alpha;
            #pragma unroll
            for (int reg = 0; reg < 4; ++reg) Cs[qb_][reg] *= alpha;

            // p = exp2(s - mn), pack bf16 pairs (round-half-up), 4 b64 writes
            #pragma unroll
            for (int sb = 0; sb < 4; ++sb) {
                float p0 = __builtin_amdgcn_exp2f(st[sb][qb_][0] - mn);
                float p1 = __builtin_amdgcn_exp2f(st[sb][qb_][1] - mn);
                float p2 = __builtin_amdgcn_exp2f(st[sb][qb_][2] - mn);
                float p3 = __builtin_amdgcn_exp2f(st[sb][qb_][3] - mn);
                unsigned u0 = __float_as_uint(p0) + 0x8000u;
                unsigned u1 = __float_as_uint(p1) + 0x8000u;
                unsigned u2 = __float_as_uint(p2) + 0x8000u;
                unsigned u3 = __float_as_uint(p3) + 0x8000u;
                uint2 pk;
                pk.x = __builtin_amdgcn_perm(u1, u0, 0x07060302);
                pk.y = __builtin_amdgcn_perm(u3, u2, 0x07060302);
                *(uint2*)(pT + (qb_ * 16 + m) * 144 + sb * 32 + q4 * 8) = pk;
            }
        }

        // drain wave-internal P^T writes before cross-lane B-frag reads
        __asm__ volatile("s_waitcnt lgkmcnt(0)" ::: "memory");

        // O^T += V^T·P^T ;  l-row += ones·P^T
        #pragma unroll
        for (int qb_ = 0; qb_ < 2; ++qb_) {
            short8 pf0 = *(const short8*)(pT + (qb_ * 16 + m) * 144 + q4 * 16);
            short8 pf1 = *(const short8*)(pT + (qb_ * 16 + m) * 144 + 64 + q4 * 16);
            O[0][qb_] = __builtin_amdgcn_mfma_f32_16x16x32_bf16(vf[0][0], pf0, O[0][qb_], 0, 0, 0);
            O[0][qb_] = __builtin_amdgcn_mfma_f32_16x16x32_bf16(vf[0][1], pf1, O[0][qb_], 0, 0, 0);
            O[1][qb_] = __builtin_amdgcn_mfma_f32_16x16x32_bf16(vf[1][0], pf0, O[1][qb_], 0, 0, 0);
            O[1][qb_] = __builtin_amdgcn_mfma_f32_16x16x32_bf16(vf[1][1], pf1, O[1][qb_], 0, 0, 0);
            Cs[qb_]   = __builtin_amdgcn_mfma_f32_16x16x32_bf16(onesf, pf0, Cs[qb_], 0, 0, 0);
            Cs[qb_]   = __builtin_amdgcn_mfma_f32_16x16x32_bf16(onesf, pf1, Cs[qb_], 0, 0, 0);
        }
    }

    // epilogue: l = Cs row 0 (quad-0 lanes) broadcast; write fp32 (B,T,H,D)
    const int b = bh >> 2, h = bh & 3;
    #pragma unroll
    for (int qb_ = 0; qb_ < 2; ++qb_) {
        const float l = __shfl(Cs[qb_][0], m, 64);   // from quad-0 lane m
        const float inv = 1.f / l;
        const int t = qt * 32 + qb_ * 16 + m;
        float* orow = og + (((size_t)b * T_ + t) * NH_ + h) * HD_;
        #pragma unroll
        for (int db = 0; db < 2; ++db)
            *(float4*)(orow + db * 16 + q4 * 4) =
                make_float4(O[db][qb_][0] * inv, O[db][qb_][1] * inv,
                            O[db][qb_][2] * inv, O[db][qb_][3] * inv);
    }
}

// -------------------------------------------------------------------------
// Kernel 3: output projection via MFMA, hi/lo bf16 split (unchanged R5).
// -------------------------------------------------------------------------
__global__ __launch_bounds__(256) void out_proj_kernel(
    const float* __restrict__ a, const float* __restrict__ Wout,
    float* __restrict__ out)
{
    __shared__ __align__(16) unsigned short whi[64 * LROW];
    __shared__ __align__(16) unsigned short wlo[64 * LROW];

    const int tid  = threadIdx.x;
    const int wave = tid >> 6, lane = tid & 63;
    const int m    = lane & 15, q4 = lane >> 4;
    const int m0   = blockIdx.x * 64;
    const int ch   = blockIdx.y;                  // 0..1

    {
        const float4* wg = (const float4*)(Wout + (size_t)ch * 64 * DM_);
        #pragma unroll
        for (int i = 0; i < 8; ++i) {
            const int f = tid + 256 * i;
            float4 v = wg[f];
            const int row = f >> 5, k4 = f & 31;
            ushort4 h, l;
            split_bf(v.x, h.x, l.x); split_bf(v.y, h.y, l.y);
            split_bf(v.z, h.z, l.z); split_bf(v.w, h.w, l.w);
            *(ushort4*)(whi + row * LROW + k4 * 4) = h;
            *(ushort4*)(wlo + row * LROW + k4 * 4) = l;
        }
    }

    short8 Ah[4], Al[4];
    {
        const float4* xg = (const float4*)(a + (size_t)(m0 + wave * 16 + m) * DM_);
        #pragma unroll
        for (int ks = 0; ks < 4; ++ks) {
            float4 av = xg[ks * 8 + q4 * 2];
            float4 bv = xg[ks * 8 + q4 * 2 + 1];
            ushort4 h0, l0, h1, l1;
            split_bf(av.x, h0.x, l0.x); split_bf(av.y, h0.y, l0.y);
            split_bf(av.z, h0.z, l0.z); split_bf(av.w, h0.w, l0.w);
            split_bf(bv.x, h1.x, l1.x); split_bf(bv.y, h1.y, l1.y);
            split_bf(bv.z, h1.z, l1.z); split_bf(bv.w, h1.w, l1.w);
            Ah[ks] = short8{(short)h0.x, (short)h0.y, (short)h0.z, (short)h0.w,
                            (short)h1.x, (short)h1.y, (short)h1.z, (short)h1.w};
            Al[ks] = short8{(short)l0.x, (short)l0.y, (short)l0.z, (short)l0.w,
                            (short)l1.x, (short)l1.y, (short)l1.z, (short)l1.w};
        }
    }
    __syncthreads();

    #pragma unroll
    for (int nb = 0; nb < 4; ++nb) {
        floatx4 acc = {0.f, 0.f, 0.f, 0.f};
        #pragma unroll
        for (int ks = 0; ks < 4; ++ks) {
            short8 Bh = *(const short8*)(whi + (nb * 16 + m) * LROW + ks * 32 + q4 * 8);
            short8 Bl = *(const short8*)(wlo + (nb * 16 + m) * LROW + ks * 32 + q4 * 8);
            acc = __builtin_amdgcn_mfma_f32_16x16x32_bf16(Ah[ks], Bh, acc, 0, 0, 0);
            acc = __builtin_amdgcn_mfma_f32_16x16x32_bf16(Ah[ks], Bl, acc, 0, 0, 0);
            acc = __builtin_amdgcn_mfma_f32_16x16x32_bf16(Al[ks], Bh, acc, 0, 0, 0);
        }
        const int n = ch * 64 + nb * 16 + m;
        const int tok0 = m0 + wave * 16 + q4 * 4;
        #pragma unroll
        for (int reg = 0; reg < 4; ++reg)
            out[(size_t)(tok0 + reg) * DM_ + n] = acc[reg];
    }
}

// -------------------------------------------------------------------------
extern "C" void kernel_launch(void* const* d_in, const int* in_sizes, int n_in,
                              void* d_out, int out_size, void* d_ws, size_t ws_size,
                              hipStream_t stream) {
    const float* x    = (const float*)d_in[0];   // (4,4096,128) fp32
    const float* Wqkv = (const float*)d_in[1];   // (384,128)    fp32
    const float* Wout = (const float*)d_in[2];   // (128,128)    fp32
    float* out = (float*)d_out;                  // (4,4096,128) fp32

    // ws layout (bytes): q_bf 4MB | k_bf 4MB | v_t 4MB | att_ws fp32 8MB
    char* ws = (char*)d_ws;
    unsigned short* q_bf  = (unsigned short*)(ws);
    unsigned short* k_bf  = (unsigned short*)(ws + (size_t)4 * 1024 * 1024);
    unsigned short* v_t   = (unsigned short*)(ws + (size_t)8 * 1024 * 1024);
    float*          att_ws = (float*)(ws + (size_t)12 * 1024 * 1024);

    qkv_proj_kernel<<<dim3(TOKENS / 64, 6), 256, 0, stream>>>(x, Wqkv, q_bf, k_bf, v_t);
    attn_mfma_kernel<<<512, 256, 0, stream>>>(q_bf, k_bf, v_t, att_ws);
    out_proj_kernel<<<dim3(TOKENS / 64, 2), 256, 0, stream>>>(att_ws, Wout, out);
}